// Round 8
// baseline (450.915 us; speedup 1.0000x reference)
//
#include <hip/hip_runtime.h>
#include <hip/hip_bf16.h>
#include <stdint.h>

// ---------------------------------------------------------------------------
// FacebookAdaptiveSoftmax forward on MI355X (gfx950) — R8
//   out[4096, 50259] = concat(x@head_w^T, (x@t0w1^T)@t0w2^T * m0, (x@t1w1^T)@t1w2^T * m1)
//   new_head_target[4096] appended flat (as float)
// R8: ONE merged GEMM launch (head + tail0 + tail1 + zero-fills), 256-thr /
// 32KB-LDS m97 blocks with type-interleaved block ids (period 5) so MFMA-heavy
// head blocks co-reside with write-heavy tail/fill blocks on every CU (write
// BW + matrix pipe busy simultaneously). h01 = tiny 96-block pre-launch of the
// SAME kernel (bf16-out config). 8-phase kernel removed (its 128KB LDS forced
// 1 block/CU and forbade mixing).
// ---------------------------------------------------------------------------

typedef float  f32x4   __attribute__((ext_vector_type(4)));
typedef short  short8  __attribute__((ext_vector_type(8)));
typedef unsigned short ushort8 __attribute__((ext_vector_type(8)));

#define CUT0 10000
#define CUT1 40000
#define CUT2 50257
#define LDC   50259L

__device__ __forceinline__ void gload16(const void* g, void* l) {
    __builtin_amdgcn_global_load_lds(
        (__attribute__((address_space(1))) void*)(g),
        (__attribute__((address_space(3))) void*)(l), 16, 0, 0);
}

__device__ __forceinline__ unsigned short f2bf(float f) {
    unsigned int u = __float_as_uint(f);
    u += 0x7fffu + ((u >> 16) & 1u);   // round-to-nearest-even
    return (unsigned short)(u >> 16);
}

// ===========================================================================
// L0: target remap + order-preserving compaction scan (1 block, 1024 thr).
// ===========================================================================
__global__ __launch_bounds__(1024)
void scan_kernel(const int* __restrict__ tgt, float* __restrict__ outT,
                 int* __restrict__ in0, int* __restrict__ z0,
                 int* __restrict__ in1, int* __restrict__ z1,
                 int* __restrict__ cnts) {
    __shared__ int w0[16], w1[16];
    const int t = threadIdx.x;
    int f0[4], f1[4];
    int c0 = 0, c1 = 0;
#pragma unroll
    for (int j = 0; j < 4; ++j) {
        const int r = t * 4 + j;
        const int v = tgt[r];
        const int b0 = (v >= CUT0) && (v < CUT1);
        const int b1 = (v >= CUT1) && (v < CUT2);
        f0[j] = b0; f1[j] = b1;
        c0 += b0; c1 += b1;
        outT[r] = (float)(b0 ? CUT0 : (b1 ? CUT0 + 1 : v));
    }
    const int lane = t & 63, w = t >> 6;
    int s0 = c0, s1 = c1;
    for (int d = 1; d < 64; d <<= 1) {
        const int u0 = __shfl_up(s0, d, 64);
        const int u1 = __shfl_up(s1, d, 64);
        if (lane >= d) { s0 += u0; s1 += u1; }
    }
    if (lane == 63) { w0[w] = s0; w1[w] = s1; }
    __syncthreads();
    if (t == 0) {
        int a0 = 0, a1 = 0;
        for (int i = 0; i < 16; ++i) {
            const int x0 = w0[i]; w0[i] = a0; a0 += x0;
            const int x1 = w1[i]; w1[i] = a1; a1 += x1;
        }
        cnts[0] = a0; cnts[1] = a1;
    }
    __syncthreads();
    int run0 = w0[w] + (s0 - c0);
    int run1 = w1[w] + (s1 - c1);
#pragma unroll
    for (int j = 0; j < 4; ++j) {
        const int r = t * 4 + j;
        if (f0[j]) in0[run0++] = r; else z0[r - run0] = r;
        if (f1[j]) in1[run1++] = r; else z1[r - run1] = r;
    }
}

// ===========================================================================
// L1: fused casts (5 segments, f32 -> bf16, zero row padding).
// ===========================================================================
struct CastSeg {
    const float* srcA;
    const float* srcB;
    unsigned short* dst;
    long rowsA, rowsB, total8;
    int lk, pad;
};
struct CastArgs {
    CastSeg s[5];
    long grand8;
};

__global__ __launch_bounds__(256)
void cast_kernel(CastArgs a) {
    long i = blockIdx.x * 256L + threadIdx.x;
    const long stride = (long)gridDim.x * 256L;
    for (; i < a.grand8; i += stride) {
        long off = i;
        int s = 0;
        while (s < 4 && off >= a.s[s].total8) { off -= a.s[s].total8; s++; }
        const CastSeg& sg = a.s[s];
        const long e   = off << 3;
        const long row = e >> sg.lk;
        ushort8 o;
        const float* src = nullptr;
        long r2 = row;
        if (row < sg.rowsA)      src = sg.srcA;
        else if (row < sg.rowsB) { src = sg.srcB; r2 = row - sg.rowsA; }
        if (src) {
            const long col = e & ((1L << sg.lk) - 1);
            const float* p = src + (r2 << sg.lk) + col;
            const float4 v0 = *(const float4*)(p);
            const float4 v1 = *(const float4*)(p + 4);
            o[0] = f2bf(v0.x); o[1] = f2bf(v0.y); o[2] = f2bf(v0.z); o[3] = f2bf(v0.w);
            o[4] = f2bf(v1.x); o[5] = f2bf(v1.y); o[6] = f2bf(v1.z); o[7] = f2bf(v1.w);
        } else {
            o = (ushort8)0;
        }
        *(ushort8*)(sg.dst + e) = o;
    }
}

// ===========================================================================
// Unified m97 128x128 GEMM block (C = A@B^T), config-driven:
//   rowlist: null -> identity rows; else gather A rows / scatter C rows.
//   Cf (f32 out) XOR Cb (bf16 out). zlist: rows to zero-fill (idle blocks).
// Transposed coalesced epilogue through 32KB LDS (R7-proven).
// mode 0: all blocks run cfg cH (h01 pre-launch).
// mode 1: period-5 interleave over {head(cH), tail0(c0), tail1(c1)}:
//   groups g<64:  [t0, head, t0, t1, t1]
//   groups g>=64: [t0, head, t0, t0, t1]
//   -> exact totals head 2528, t0 7520, t1 2592 (grid 12640).
// ===========================================================================
struct GemmCfg {
    const unsigned short* A;
    const unsigned short* B;
    float* Cf;
    unsigned short* Cb;
    const int* rowlist;
    const int* zlist;
    long ldc;
    int K, lda, width, NB, nwg, cntSel;
};

__global__ __launch_bounds__(256)
void mega_kernel(GemmCfg cH, GemmCfg c0, GemmCfg c1, int mode,
                 const int* __restrict__ cnts) {
    __shared__ char tsm[32768];
    unsigned short* As = (unsigned short*)tsm;
    unsigned short* Bs = (unsigned short*)(tsm + 8192);

    const int tid  = threadIdx.x;
    const int lane = tid & 63;
    const int wave = tid >> 6;
    const int wr   = wave >> 1;
    const int wc   = wave & 1;

    // ---- select config + local index (block-uniform) ----
    GemmCfg c; int lidx;
    if (mode == 0) {
        c = cH; lidx = blockIdx.x;
    } else {
        const int id = blockIdx.x;
        const int g = id / 5, r = id - 5 * g;
        if (r == 1) { c = cH; lidx = g; }
        else if (g < 64) {
            if (r == 0 || r == 2) { c = c0; lidx = 2 * g + (r == 2 ? 1 : 0); }
            else                  { c = c1; lidx = 2 * g + (r == 4 ? 1 : 0); }
        } else {
            if (r == 4) { c = c1; lidx = 128 + (g - 64); }
            else        { c = c0; lidx = 128 + 3 * (g - 64) + (r == 0 ? 0 : (r == 2 ? 1 : 2)); }
        }
    }
    const int cnt = (c.cntSel < 0) ? 4096 : cnts[c.cntSel];

    // ---- bijective XCD chunk + GROUP_M=8 (nwg % 8 == 0 for all cfgs) ----
    const int NB = c.NB, nwg = c.nwg;
    const int q = nwg >> 3, rr = nwg & 7;
    const int xcd = lidx & 7, loc = lidx >> 3;
    const int L = (xcd < rr ? xcd * (q + 1) : rr * (q + 1) + (xcd - rr) * q) + loc;
    const int g2 = L / (NB << 3);
    const int t2 = L - g2 * (NB << 3);
    const long bm = (g2 << 3) + (t2 & 7);
    const long bn = t2 >> 3;

    const bool active = (int)(bm * 128) < cnt;

    if (active) {
        const int cm1 = cnt - 1;
        const int s_row = tid >> 2;
        const int s_col = (tid & 3) << 3;
        const int gi0 = (int)(bm * 128) + s_row;
        const int gi1 = gi0 + 64;
        int r0, r1;
        if (c.rowlist) {
            r0 = c.rowlist[gi0 < cnt ? gi0 : cm1];
            r1 = c.rowlist[gi1 < cnt ? gi1 : cm1];
        } else {
            r0 = gi0; r1 = gi1;
        }

        const unsigned short* pA0 = c.A + (long)r0 * c.lda + s_col;
        const unsigned short* pA1 = c.A + (long)r1 * c.lda + s_col;
        const unsigned short* pB  = c.B + (bn * 128 + s_row) * (long)c.K + s_col;

        char* asb = (char*)As + wave * 1024;
        char* bsb = (char*)Bs + wave * 1024;

        f32x4 acc[4][4];
#pragma unroll
        for (int m = 0; m < 4; m++)
#pragma unroll
            for (int n = 0; n < 4; n++) acc[m][n] = (f32x4){0.f, 0.f, 0.f, 0.f};

        const int f_r = lane & 15;
        const int f_k = (lane >> 4) << 3;

        for (int k0 = 0; k0 < c.K; k0 += 32) {
            gload16(pA0 + k0,            asb);
            gload16(pA1 + k0,            asb + 4096);
            gload16(pB + k0,             bsb);
            gload16(pB + k0 + 64L * c.K, bsb + 4096);
            __syncthreads();

            short8 af[4], bfr[4];
#pragma unroll
            for (int m = 0; m < 4; m++)
                af[m] = *(const short8*)&As[(wr * 64 + m * 16 + f_r) * 32 + f_k];
#pragma unroll
            for (int n = 0; n < 4; n++)
                bfr[n] = *(const short8*)&Bs[(wc * 64 + n * 16 + f_r) * 32 + f_k];

            // swapped operands: D row field = B-row = output col
#pragma unroll
            for (int m = 0; m < 4; m++)
#pragma unroll
                for (int n = 0; n < 4; n++)
                    acc[m][n] = __builtin_amdgcn_mfma_f32_16x16x32_bf16(
                        bfr[n], af[m], acc[m][n], 0, 0, 0);
            __syncthreads();
        }

        // ---- transposed coalesced epilogue: LDS [64][128] f32, 2 passes ----
        const int c_a  = lane & 15;
        const int colL = (lane & 31) * 4;
        for (int h = 0; h < 2; ++h) {
            __syncthreads();
            if (wr == h) {
#pragma unroll
                for (int m = 0; m < 4; ++m) {
                    const int rl = m * 16 + c_a;
#pragma unroll
                    for (int n = 0; n < 4; ++n) {
                        const int slot = wc * 16 + n * 4 + (lane >> 4);
                        const int sl = slot ^ (rl & 7);
                        *(f32x4*)(tsm + rl * 512 + sl * 16) = acc[m][n];
                    }
                }
            }
            __syncthreads();
#pragma unroll
            for (int it = 0; it < 8; ++it) {
                const int rl = wave * 16 + it * 2 + (lane >> 5);
                const int gri = (int)(bm * 128) + h * 64 + rl;
                if (gri < cnt) {
                    const int sl = (lane & 31) ^ (rl & 7);
                    const f32x4 v = *(const f32x4*)(tsm + rl * 512 + sl * 16);
                    const long orow = c.rowlist ? (long)c.rowlist[gri] : (long)gri;
                    const int col = (int)(bn * 128) + colL;
                    if (c.Cf) {
                        float* rp = c.Cf + orow * c.ldc;
                        if (col + 3 < c.width) {
                            __builtin_memcpy(rp + col, &v, 16);
                        } else {
#pragma unroll
                            for (int j = 0; j < 4; ++j)
                                if (col + j < c.width) rp[col + j] = v[j];
                        }
                    } else {
                        unsigned short* rp = c.Cb + orow * c.ldc;
                        ushort4 o;
                        o.x = f2bf(v[0]); o.y = f2bf(v[1]);
                        o.z = f2bf(v[2]); o.w = f2bf(v[3]);
                        if (col + 3 < c.width) {
                            *(ushort4*)(rp + col) = o;
                        } else {
                            unsigned short tmp[4] = {o.x, o.y, o.z, o.w};
#pragma unroll
                            for (int j = 0; j < 4; ++j)
                                if (col + j < c.width) rp[col + j] = tmp[j];
                        }
                    }
                }
            }
        }
    }

    // ---- zero-fill of masked tail rows (idle blocks start immediately) ----
    if (c.zlist) {
        const f32x4 zv = {0.f, 0.f, 0.f, 0.f};
        const int zc = 4096 - cnt;
        for (int s = lidx; s < zc; s += nwg) {
            const int rrow = c.zlist[s];
            float* base = c.Cf + (long)rrow * c.ldc;
            for (int j = tid * 4; j + 3 < c.width; j += 1024)
                __builtin_memcpy(base + j, &zv, 16);
            for (int j = (c.width & ~3) + tid; j < c.width; j += 256)
                base[j] = 0.f;
        }
    }
}

extern "C" void kernel_launch(void* const* d_in, const int* in_sizes, int n_in,
                              void* d_out, int out_size, void* d_ws, size_t ws_size,
                              hipStream_t stream) {
    const float* x      = (const float*)d_in[0];   // [4096,1024]
    const int*   target = (const int*)  d_in[1];   // [4096]
    const float* head_w = (const float*)d_in[2];   // [10002,1024]
    const float* t0_w1  = (const float*)d_in[3];   // [256,1024]
    const float* t0_w2  = (const float*)d_in[4];   // [30000,256]
    const float* t1_w1  = (const float*)d_in[5];   // [64,1024]
    const float* t1_w2  = (const float*)d_in[6];   // [10257,64]
    float* out = (float*)d_out;

    // ---- ws layout (bytes) ----
    char* ws = (char*)d_ws;
    unsigned short* xb    = (unsigned short*)(ws + 0);          // 4096x1024
    unsigned short* hwb   = (unsigned short*)(ws + 8388608);    // 10240x1024
    unsigned short* w01b  = (unsigned short*)(ws + 29360128);   // 512x1024 (t0w1|t1w1|0)
    unsigned short* t0w2b = (unsigned short*)(ws + 30408704);   // 30208x256
    unsigned short* t1w2b = (unsigned short*)(ws + 45875200);   // 10496x64
    unsigned short* h01   = (unsigned short*)(ws + 47218688);   // 4096x384 bf16
    int*            in0   = (int*)(ws + 50364416);              // 4096
    int*            z0l   = (int*)(ws + 50380800);              // 4096
    int*            in1   = (int*)(ws + 50397184);              // 4096
    int*            z1l   = (int*)(ws + 50413568);              // 4096
    int*            cnts  = (int*)(ws + 50429952);              // 2

    // ---- L0: scan (target remap + compaction lists) ----
    scan_kernel<<<1, 1024, 0, stream>>>(target, out + 4096L * LDC,
                                        in0, z0l, in1, z1l, cnts);

    // ---- L1: casts ----
    CastArgs ca;
    ca.s[0] = {x,      nullptr, xb,    4096,  4096,  524288,  10, 0};
    ca.s[1] = {head_w, nullptr, hwb,   10002, 10002, 1310720, 10, 0};
    ca.s[2] = {t0_w1,  t1_w1,   w01b,  256,   320,   65536,   10, 0};
    ca.s[3] = {t0_w2,  nullptr, t0w2b, 30000, 30000, 966656,  8,  0};
    ca.s[4] = {t1_w2,  nullptr, t1w2b, 10257, 10257, 83968,   6,  0};
    ca.grand8 = 524288 + 1310720 + 65536 + 966656 + 83968;  // 2951168
    cast_kernel<<<2048, 256, 0, stream>>>(ca);

    // ---- configs ----
    GemmCfg cH01, cHead, cT0, cT1;
    // h01: h01[4096,384] = bf16(xb @ w01b^T), 32bm x 3bn = 96 blocks
    cH01  = {xb, w01b, nullptr, h01, nullptr, nullptr, 384L,
             1024, 1024, 384, 3, 96, -1};
    // head: out[:,0:10002] = xb @ hwb^T, 32bm x 79bn = 2528 blocks
    cHead = {xb, hwb, out, nullptr, nullptr, nullptr, LDC,
             1024, 1024, 10002, 79, 2528, -1};
    // tail0: out[in0,10002:40002] = h0[in0] @ t0w2^T, 32bm x 235bn = 7520
    cT0   = {h01, t0w2b, out + 10002, nullptr, in0, z0l, LDC,
             256, 384, 30000, 235, 7520, 0};
    // tail1: out[in1,40002:50259] = h1[in1] @ t1w2^T, 32bm x 81bn = 2592
    cT1   = {h01 + 256, t1w2b, out + 40002, nullptr, in1, z1l, LDC,
             64, 384, 10257, 81, 2592, 1};

    // ---- L2: h01 pre-launch (96 blocks, same kernel, mode 0) ----
    mega_kernel<<<dim3(96), 256, 0, stream>>>(cH01, cT0, cT1, 0, cnts);

    // ---- L3: merged head + tail0 + tail1 + fills (12640 blocks, mode 1) ----
    mega_kernel<<<dim3(12640), 256, 0, stream>>>(cHead, cT0, cT1, 1, cnts);
}

// Round 9
// 415.945 us; speedup vs baseline: 1.0841x; 1.0841x over previous
//
#include <hip/hip_runtime.h>
#include <hip/hip_bf16.h>
#include <stdint.h>

// ---------------------------------------------------------------------------
// FacebookAdaptiveSoftmax forward on MI355X (gfx950) — R9
//   out[4096, 50259] = concat(x@head_w^T, (x@t0w1^T)@t0w2^T * m0, (x@t1w1^T)@t1w2^T * m1)
//   new_head_target[4096] appended flat (as float)
// R9 vs R7 (R8 reverted): head + h01 moved from the 8-phase 256^2 kernel
// (whose counted-vmcnt was found structurally drained -> ~m97-class perf at
// 1 block/CU, plus a latent 2-load race) onto the PROVEN m97 128^2 path
// (32KB LDS, 4-5 blocks/CU inter-block overlap, transposed coalesced
// epilogue). Tails / fills / casts / scan byte-identical to R7.
// ---------------------------------------------------------------------------

typedef float  f32x4   __attribute__((ext_vector_type(4)));
typedef short  short8  __attribute__((ext_vector_type(8)));
typedef unsigned short ushort8 __attribute__((ext_vector_type(8)));

#define CUT0 10000
#define CUT1 40000
#define CUT2 50257
#define LDC   50259L

__device__ __forceinline__ void gload16(const void* g, void* l) {
    __builtin_amdgcn_global_load_lds(
        (__attribute__((address_space(1))) void*)(g),
        (__attribute__((address_space(3))) void*)(l), 16, 0, 0);
}

__device__ __forceinline__ unsigned short f2bf(float f) {
    unsigned int u = __float_as_uint(f);
    u += 0x7fffu + ((u >> 16) & 1u);   // round-to-nearest-even
    return (unsigned short)(u >> 16);
}

// ===========================================================================
// L0: target remap + order-preserving compaction scan (1 block, 1024 thr).
// ===========================================================================
__global__ __launch_bounds__(1024)
void scan_kernel(const int* __restrict__ tgt, float* __restrict__ outT,
                 int* __restrict__ in0, int* __restrict__ z0,
                 int* __restrict__ in1, int* __restrict__ z1,
                 int* __restrict__ cnts) {
    __shared__ int w0[16], w1[16];
    const int t = threadIdx.x;
    int f0[4], f1[4];
    int c0 = 0, c1 = 0;
#pragma unroll
    for (int j = 0; j < 4; ++j) {
        const int r = t * 4 + j;
        const int v = tgt[r];
        const int b0 = (v >= CUT0) && (v < CUT1);
        const int b1 = (v >= CUT1) && (v < CUT2);
        f0[j] = b0; f1[j] = b1;
        c0 += b0; c1 += b1;
        outT[r] = (float)(b0 ? CUT0 : (b1 ? CUT0 + 1 : v));
    }
    const int lane = t & 63, w = t >> 6;
    int s0 = c0, s1 = c1;
    for (int d = 1; d < 64; d <<= 1) {
        const int u0 = __shfl_up(s0, d, 64);
        const int u1 = __shfl_up(s1, d, 64);
        if (lane >= d) { s0 += u0; s1 += u1; }
    }
    if (lane == 63) { w0[w] = s0; w1[w] = s1; }
    __syncthreads();
    if (t == 0) {
        int a0 = 0, a1 = 0;
        for (int i = 0; i < 16; ++i) {
            const int x0 = w0[i]; w0[i] = a0; a0 += x0;
            const int x1 = w1[i]; w1[i] = a1; a1 += x1;
        }
        cnts[0] = a0; cnts[1] = a1;
    }
    __syncthreads();
    int run0 = w0[w] + (s0 - c0);
    int run1 = w1[w] + (s1 - c1);
#pragma unroll
    for (int j = 0; j < 4; ++j) {
        const int r = t * 4 + j;
        if (f0[j]) in0[run0++] = r; else z0[r - run0] = r;
        if (f1[j]) in1[run1++] = r; else z1[r - run1] = r;
    }
}

// ===========================================================================
// L1: fused casts (5 segments, f32 -> bf16, zero row padding).
// ===========================================================================
struct CastSeg {
    const float* srcA;
    const float* srcB;
    unsigned short* dst;
    long rowsA, rowsB, total8;
    int lk, pad;
};
struct CastArgs {
    CastSeg s[5];
    long grand8;
};

__global__ __launch_bounds__(256)
void cast_kernel(CastArgs a) {
    long i = blockIdx.x * 256L + threadIdx.x;
    const long stride = (long)gridDim.x * 256L;
    for (; i < a.grand8; i += stride) {
        long off = i;
        int s = 0;
        while (s < 4 && off >= a.s[s].total8) { off -= a.s[s].total8; s++; }
        const CastSeg& sg = a.s[s];
        const long e   = off << 3;
        const long row = e >> sg.lk;
        ushort8 o;
        const float* src = nullptr;
        long r2 = row;
        if (row < sg.rowsA)      src = sg.srcA;
        else if (row < sg.rowsB) { src = sg.srcB; r2 = row - sg.rowsA; }
        if (src) {
            const long col = e & ((1L << sg.lk) - 1);
            const float* p = src + (r2 << sg.lk) + col;
            const float4 v0 = *(const float4*)(p);
            const float4 v1 = *(const float4*)(p + 4);
            o[0] = f2bf(v0.x); o[1] = f2bf(v0.y); o[2] = f2bf(v0.z); o[3] = f2bf(v0.w);
            o[4] = f2bf(v1.x); o[5] = f2bf(v1.y); o[6] = f2bf(v1.z); o[7] = f2bf(v1.w);
        } else {
            o = (ushort8)0;
        }
        *(ushort8*)(sg.dst + e) = o;
    }
}

// ===========================================================================
// L2: head + h01 on the m97 128x128 structure (dual-config).
//   blocks [0, nblk0): head  C0f = A @ B0^T (f32, transposed coalesced epi)
//   blocks [nblk0,..): h01   C1b = A @ B1^T (bf16, direct stores, ldc=384)
// K = lda = 1024 for both. Swapped operands (D row field = B-row = out col).
// ===========================================================================
__global__ __launch_bounds__(256)
void gemm_head_kernel(const unsigned short* __restrict__ A,
                      const unsigned short* __restrict__ B0,
                      float* __restrict__ C0, int width0, int NB0, int nblk0,
                      const unsigned short* __restrict__ B1,
                      unsigned short* __restrict__ C1, int width1, int NB1) {
    __shared__ char tsm[32768];
    unsigned short* As = (unsigned short*)tsm;
    unsigned short* Bs = (unsigned short*)(tsm + 8192);

    const int tid  = threadIdx.x;
    const int lane = tid & 63;
    const int wave = tid >> 6;
    const int wr   = wave >> 1;
    const int wc   = wave & 1;

    const bool isH = (int)blockIdx.x < nblk0;
    const unsigned short* B = isH ? B0 : B1;
    const int NB    = isH ? NB0 : NB1;
    const int width = isH ? width0 : width1;
    const int lbid  = isH ? blockIdx.x : blockIdx.x - nblk0;
    const int nwg   = isH ? nblk0 : (int)gridDim.x - nblk0;

    // bijective XCD chunk + GROUP_M=8 (nwg % 8 == 0: 2528, 96)
    const int q = nwg >> 3, r = nwg & 7;
    const int xcd = lbid & 7, loc = lbid >> 3;
    const int L = (xcd < r ? xcd * (q + 1) : r * (q + 1) + (xcd - r) * q) + loc;
    const int g = L / (NB << 3);
    const int t = L - g * (NB << 3);
    const long bm = (g << 3) + (t & 7);
    const long bn = t >> 3;

    const int s_row = tid >> 2;
    const int s_col = (tid & 3) << 3;

    const unsigned short* pA0 = A + (bm * 128 + s_row) * 1024L + s_col;
    const unsigned short* pA1 = pA0 + 64L * 1024L;
    const unsigned short* pB  = B + (bn * 128 + s_row) * 1024L + s_col;

    char* asb = (char*)As + wave * 1024;
    char* bsb = (char*)Bs + wave * 1024;

    f32x4 acc[4][4];
#pragma unroll
    for (int m = 0; m < 4; m++)
#pragma unroll
        for (int n = 0; n < 4; n++) acc[m][n] = (f32x4){0.f, 0.f, 0.f, 0.f};

    const int f_r = lane & 15;
    const int f_k = (lane >> 4) << 3;

    for (int k0 = 0; k0 < 1024; k0 += 32) {
        gload16(pA0 + k0,           asb);
        gload16(pA1 + k0,           asb + 4096);
        gload16(pB + k0,            bsb);
        gload16(pB + k0 + 64L * 1024L, bsb + 4096);
        __syncthreads();

        short8 af[4], bfr[4];
#pragma unroll
        for (int m = 0; m < 4; m++)
            af[m] = *(const short8*)&As[(wr * 64 + m * 16 + f_r) * 32 + f_k];
#pragma unroll
        for (int n = 0; n < 4; n++)
            bfr[n] = *(const short8*)&Bs[(wc * 64 + n * 16 + f_r) * 32 + f_k];

        // swapped operands: D row field = B-row = output col
#pragma unroll
        for (int m = 0; m < 4; m++)
#pragma unroll
            for (int n = 0; n < 4; n++)
                acc[m][n] = __builtin_amdgcn_mfma_f32_16x16x32_bf16(
                    bfr[n], af[m], acc[m][n], 0, 0, 0);
        __syncthreads();
    }

    if (isH) {
        // ---- transposed coalesced epilogue: LDS [64][128] f32, 2 passes ----
        const int c_a  = lane & 15;
        const int colL = (lane & 31) * 4;
        for (int h = 0; h < 2; ++h) {
            __syncthreads();
            if (wr == h) {
#pragma unroll
                for (int m = 0; m < 4; ++m) {
                    const int rl = m * 16 + c_a;
#pragma unroll
                    for (int n = 0; n < 4; ++n) {
                        const int slot = wc * 16 + n * 4 + (lane >> 4);
                        const int sl = slot ^ (rl & 7);
                        *(f32x4*)(tsm + rl * 512 + sl * 16) = acc[m][n];
                    }
                }
            }
            __syncthreads();
#pragma unroll
            for (int it = 0; it < 8; ++it) {
                const int rl = wave * 16 + it * 2 + (lane >> 5);
                const long grow = bm * 128 + h * 64 + rl;
                const int sl = (lane & 31) ^ (rl & 7);
                const f32x4 v = *(const f32x4*)(tsm + rl * 512 + sl * 16);
                float* rp = C0 + grow * LDC;
                const int col = (int)(bn * 128) + colL;
                if (col + 3 < width) {
                    __builtin_memcpy(rp + col, &v, 16);
                } else {
#pragma unroll
                    for (int j = 0; j < 4; ++j)
                        if (col + j < width) rp[col + j] = v[j];
                }
            }
        }
    } else {
        // ---- h01 bf16 direct stores (3 MB total; all cols in-range) ----
        const int c_a  = lane & 15;
        const int c_b4 = (lane >> 4) << 2;
#pragma unroll
        for (int m = 0; m < 4; m++) {
            const long grow = bm * 128 + wr * 64 + m * 16 + c_a;
            unsigned short* rp = C1 + grow * 384L;
#pragma unroll
            for (int n = 0; n < 4; n++) {
                const int gcb = (int)(bn * 128) + wc * 64 + n * 16 + c_b4;
                const f32x4 v = acc[m][n];
                ushort4 o;
                o.x = f2bf(v[0]); o.y = f2bf(v[1]); o.z = f2bf(v[2]); o.w = f2bf(v[3]);
                if (gcb + 3 < width) {
                    *(ushort4*)(rp + gcb) = o;
                } else {
                    unsigned short tmp[4] = {o.x, o.y, o.z, o.w};
#pragma unroll
                    for (int j = 0; j < 4; ++j)
                        if (gcb + j < width) rp[gcb + j] = tmp[j];
                }
            }
        }
    }
}

// ===========================================================================
// L3: compacted tails, m97-128^2 dual-config, transposed coalesced epilogue
// (byte-identical to R7). Idle/finished blocks zero-fill masked tail rows.
// ===========================================================================
__global__ __launch_bounds__(256)
void gemm_tails_kernel(const unsigned short* __restrict__ A0,
                       const unsigned short* __restrict__ B0,
                       float* __restrict__ C0,
                       int K0, int lda0, int width0, int NB0, int nblk0,
                       const unsigned short* __restrict__ A1,
                       const unsigned short* __restrict__ B1,
                       float* __restrict__ C1,
                       int K1, int lda1, int width1, int NB1,
                       const int* __restrict__ in0,
                       const int* __restrict__ in1,
                       const int* __restrict__ z0,
                       const int* __restrict__ z1,
                       const int* __restrict__ cnts) {
    __shared__ char tsm[32768];
    unsigned short* As = (unsigned short*)tsm;
    unsigned short* Bs = (unsigned short*)(tsm + 8192);

    const int tid  = threadIdx.x;
    const int lane = tid & 63;
    const int wave = tid >> 6;
    const int wr   = wave >> 1;
    const int wc   = wave & 1;

    const bool is0 = (int)blockIdx.x < nblk0;
    const unsigned short* A = is0 ? A0 : A1;
    const unsigned short* B = is0 ? B0 : B1;
    float* Cf               = is0 ? C0 : C1;
    const int* rowlist      = is0 ? in0 : in1;
    const int cnt           = cnts[is0 ? 0 : 1];
    const int K     = is0 ? K0 : K1;
    const int lda   = is0 ? lda0 : lda1;
    const int width = is0 ? width0 : width1;
    const int NB    = is0 ? NB0 : NB1;
    const int lbid  = is0 ? blockIdx.x : blockIdx.x - nblk0;
    const int nwg   = is0 ? nblk0 : (int)gridDim.x - nblk0;

    const int q = nwg >> 3, r = nwg & 7;
    const int xcd = lbid & 7, loc = lbid >> 3;
    const int L = (xcd < r ? xcd * (q + 1) : r * (q + 1) + (xcd - r) * q) + loc;
    const int g = L / (NB << 3);
    const int t = L - g * (NB << 3);
    const long bm = (g << 3) + (t & 7);
    const long bn = t >> 3;

    const bool active = (int)(bm * 128) < cnt;

    if (active) {
        const int cm1 = cnt - 1;
        const int s_row = tid >> 2;
        const int s_col = (tid & 3) << 3;
        const int gi0 = (int)(bm * 128) + s_row;
        const int gi1 = gi0 + 64;
        const int r0 = rowlist[gi0 < cnt ? gi0 : cm1];
        const int r1 = rowlist[gi1 < cnt ? gi1 : cm1];

        const unsigned short* pA0 = A + (long)r0 * lda + s_col;
        const unsigned short* pA1 = A + (long)r1 * lda + s_col;
        const unsigned short* pB  = B + (bn * 128 + s_row) * (long)K + s_col;

        char* asb = (char*)As + wave * 1024;
        char* bsb = (char*)Bs + wave * 1024;

        f32x4 acc[4][4];
#pragma unroll
        for (int m = 0; m < 4; m++)
#pragma unroll
            for (int n = 0; n < 4; n++) acc[m][n] = (f32x4){0.f, 0.f, 0.f, 0.f};

        const int f_r = lane & 15;
        const int f_k = (lane >> 4) << 3;

        for (int k0 = 0; k0 < K; k0 += 32) {
            gload16(pA0 + k0,          asb);
            gload16(pA1 + k0,          asb + 4096);
            gload16(pB + k0,           bsb);
            gload16(pB + k0 + 64L * K, bsb + 4096);
            __syncthreads();

            short8 af[4], bfr[4];
#pragma unroll
            for (int m = 0; m < 4; m++)
                af[m] = *(const short8*)&As[(wr * 64 + m * 16 + f_r) * 32 + f_k];
#pragma unroll
            for (int n = 0; n < 4; n++)
                bfr[n] = *(const short8*)&Bs[(wc * 64 + n * 16 + f_r) * 32 + f_k];

#pragma unroll
            for (int m = 0; m < 4; m++)
#pragma unroll
                for (int n = 0; n < 4; n++)
                    acc[m][n] = __builtin_amdgcn_mfma_f32_16x16x32_bf16(
                        bfr[n], af[m], acc[m][n], 0, 0, 0);
            __syncthreads();
        }

        // ---- transposed coalesced epilogue: LDS [64][128] f32, 2 passes ----
        const int c_a  = lane & 15;
        const int colL = (lane & 31) * 4;
        for (int h = 0; h < 2; ++h) {
            __syncthreads();
            if (wr == h) {
#pragma unroll
                for (int m = 0; m < 4; ++m) {
                    const int rl = m * 16 + c_a;
#pragma unroll
                    for (int n = 0; n < 4; ++n) {
                        const int slot = wc * 16 + n * 4 + (lane >> 4);
                        const int sl = slot ^ (rl & 7);
                        *(f32x4*)(tsm + rl * 512 + sl * 16) = acc[m][n];
                    }
                }
            }
            __syncthreads();
#pragma unroll
            for (int it = 0; it < 8; ++it) {
                const int rl = wave * 16 + it * 2 + (lane >> 5);
                const int gri = (int)(bm * 128) + h * 64 + rl;
                if (gri < cnt) {
                    const int sl = (lane & 31) ^ (rl & 7);
                    const f32x4 v = *(const f32x4*)(tsm + rl * 512 + sl * 16);
                    const long orow = rowlist[gri];
                    float* rp = Cf + orow * LDC;
                    const int col = (int)(bn * 128) + colL;
                    if (col + 3 < width) {
                        __builtin_memcpy(rp + col, &v, 16);
                    } else {
#pragma unroll
                        for (int j = 0; j < 4; ++j)
                            if (col + j < width) rp[col + j] = v[j];
                    }
                }
            }
        }
    }

    // ---- zero-fill of masked tail rows (idle blocks start immediately) ----
    {
        const f32x4 zv = {0.f, 0.f, 0.f, 0.f};
        const int zc = 4096 - cnt;
        const int* zl = is0 ? z0 : z1;
        for (int s = lbid; s < zc; s += nwg) {
            const int rr = zl[s];
            float* base = Cf + (long)rr * LDC;
            for (int j = tid * 4; j + 3 < width; j += 1024)
                __builtin_memcpy(base + j, &zv, 16);
            for (int j = (width & ~3) + tid; j < width; j += 256)
                base[j] = 0.f;
        }
    }
}

extern "C" void kernel_launch(void* const* d_in, const int* in_sizes, int n_in,
                              void* d_out, int out_size, void* d_ws, size_t ws_size,
                              hipStream_t stream) {
    const float* x      = (const float*)d_in[0];   // [4096,1024]
    const int*   target = (const int*)  d_in[1];   // [4096]
    const float* head_w = (const float*)d_in[2];   // [10002,1024]
    const float* t0_w1  = (const float*)d_in[3];   // [256,1024]
    const float* t0_w2  = (const float*)d_in[4];   // [30000,256]
    const float* t1_w1  = (const float*)d_in[5];   // [64,1024]
    const float* t1_w2  = (const float*)d_in[6];   // [10257,64]
    float* out = (float*)d_out;

    // ---- ws layout (bytes) ----
    char* ws = (char*)d_ws;
    unsigned short* xb    = (unsigned short*)(ws + 0);          // 4096x1024
    unsigned short* hwb   = (unsigned short*)(ws + 8388608);    // 10240x1024
    unsigned short* w01b  = (unsigned short*)(ws + 29360128);   // 512x1024 (t0w1|t1w1|0)
    unsigned short* t0w2b = (unsigned short*)(ws + 30408704);   // 30208x256
    unsigned short* t1w2b = (unsigned short*)(ws + 45875200);   // 10496x64
    unsigned short* h01   = (unsigned short*)(ws + 47218688);   // 4096x384 bf16
    int*            in0   = (int*)(ws + 50364416);              // 4096
    int*            z0l   = (int*)(ws + 50380800);              // 4096
    int*            in1   = (int*)(ws + 50397184);              // 4096
    int*            z1l   = (int*)(ws + 50413568);              // 4096
    int*            cnts  = (int*)(ws + 50429952);              // 2

    // ---- L0: scan (target remap + compaction lists) ----
    scan_kernel<<<1, 1024, 0, stream>>>(target, out + 4096L * LDC,
                                        in0, z0l, in1, z1l, cnts);

    // ---- L1: casts ----
    CastArgs ca;
    ca.s[0] = {x,      nullptr, xb,    4096,  4096,  524288,  10, 0};
    ca.s[1] = {head_w, nullptr, hwb,   10002, 10002, 1310720, 10, 0};
    ca.s[2] = {t0_w1,  t1_w1,   w01b,  256,   320,   65536,   10, 0};
    ca.s[3] = {t0_w2,  nullptr, t0w2b, 30000, 30000, 966656,  8,  0};
    ca.s[4] = {t1_w2,  nullptr, t1w2b, 10257, 10257, 83968,   6,  0};
    ca.grand8 = 524288 + 1310720 + 65536 + 966656 + 83968;  // 2951168
    cast_kernel<<<2048, 256, 0, stream>>>(ca);

    // ---- L2: head (2528 blocks) + h01 (96 blocks), m97 128^2 dual ----
    gemm_head_kernel<<<dim3(2624), 256, 0, stream>>>(
        xb, hwb, out, 10002, 79, 2528,
        w01b, h01, 384, 3);

    // ---- L3: compacted tails + zero-fills (early-exit blocks fill) ----
    gemm_tails_kernel<<<dim3(10112), 256, 0, stream>>>(
        h01,       t0w2b, out + 10002, 256, 384, 30000, 235, 7520,
        h01 + 256, t1w2b, out + 40002, 64,  384, 10257, 81,
        in0, in1, z0l, z1l, cnts);
}

// Round 10
// 365.503 us; speedup vs baseline: 1.2337x; 1.1380x over previous
//
#include <hip/hip_runtime.h>
#include <hip/hip_bf16.h>
#include <stdint.h>

// ---------------------------------------------------------------------------
// FacebookAdaptiveSoftmax forward on MI355X (gfx950) — R10
//   out[4096, 50259] = concat(x@head_w^T, (x@t0w1^T)@t0w2^T * m0, (x@t1w1^T)@t1w2^T * m1)
//   new_head_target[4096] appended flat (as float)
// R10 = R7 base (best: 375us; R8/R9 m97-head experiments reverted) with L3
// (tails) reworked, L0/L1/L2 byte-identical to R7:
//   * tails BK=64: one stage+drain per 64 K (tail0 4 iters vs 8, tail1 1 vs 2)
//     -- m233: stage+vmcnt-drain+barrier is ~72% of the 2-phase cycle cost.
//     Sequential k-halves keep frag VGPR low; rule-21 swizzle pair
//     (src chunk ^ row&7  <->  ds_read col ^ (row&7)<<4) keeps reads 2-way.
//   * non-temporal scalar stores on all L3 f32 output/fill writes: the 660MB
//     write stream stops evicting B-panels/h01 from the 4MB/XCD L2s.
// ---------------------------------------------------------------------------

typedef float  f32x4   __attribute__((ext_vector_type(4)));
typedef short  short8  __attribute__((ext_vector_type(8)));
typedef unsigned short ushort8 __attribute__((ext_vector_type(8)));

#define CUT0 10000
#define CUT1 40000
#define CUT2 50257
#define LDC   50259L

__device__ __forceinline__ void gload16(const void* g, void* l) {
    __builtin_amdgcn_global_load_lds(
        (__attribute__((address_space(1))) void*)(g),
        (__attribute__((address_space(3))) void*)(l), 16, 0, 0);
}

__device__ __forceinline__ unsigned short f2bf(float f) {
    unsigned int u = __float_as_uint(f);
    u += 0x7fffu + ((u >> 16) & 1u);   // round-to-nearest-even
    return (unsigned short)(u >> 16);
}

__device__ __forceinline__ short8 dsr128(unsigned addr) {
    f32x4 r;
    asm volatile("ds_read_b128 %0, %1" : "=v"(r) : "v"(addr));
    return __builtin_bit_cast(short8, r);
}

__device__ __forceinline__ f32x4 mfma16(short8 a, short8 b, f32x4 c) {
    return __builtin_amdgcn_mfma_f32_16x16x32_bf16(a, b, c, 0, 0, 0);
}

__device__ __forceinline__ void nt4(float* p, f32x4 v) {
    // scalar nt stores: odd ldc -> only 4B alignment guaranteed
    __builtin_nontemporal_store(v[0], p);
    __builtin_nontemporal_store(v[1], p + 1);
    __builtin_nontemporal_store(v[2], p + 2);
    __builtin_nontemporal_store(v[3], p + 3);
}

// ===========================================================================
// L0: target remap + order-preserving compaction scan (1 block, 1024 thr).
// ===========================================================================
__global__ __launch_bounds__(1024)
void scan_kernel(const int* __restrict__ tgt, float* __restrict__ outT,
                 int* __restrict__ in0, int* __restrict__ z0,
                 int* __restrict__ in1, int* __restrict__ z1,
                 int* __restrict__ cnts) {
    __shared__ int w0[16], w1[16];
    const int t = threadIdx.x;
    int f0[4], f1[4];
    int c0 = 0, c1 = 0;
#pragma unroll
    for (int j = 0; j < 4; ++j) {
        const int r = t * 4 + j;
        const int v = tgt[r];
        const int b0 = (v >= CUT0) && (v < CUT1);
        const int b1 = (v >= CUT1) && (v < CUT2);
        f0[j] = b0; f1[j] = b1;
        c0 += b0; c1 += b1;
        outT[r] = (float)(b0 ? CUT0 : (b1 ? CUT0 + 1 : v));
    }
    const int lane = t & 63, w = t >> 6;
    int s0 = c0, s1 = c1;
    for (int d = 1; d < 64; d <<= 1) {
        const int u0 = __shfl_up(s0, d, 64);
        const int u1 = __shfl_up(s1, d, 64);
        if (lane >= d) { s0 += u0; s1 += u1; }
    }
    if (lane == 63) { w0[w] = s0; w1[w] = s1; }
    __syncthreads();
    if (t == 0) {
        int a0 = 0, a1 = 0;
        for (int i = 0; i < 16; ++i) {
            const int x0 = w0[i]; w0[i] = a0; a0 += x0;
            const int x1 = w1[i]; w1[i] = a1; a1 += x1;
        }
        cnts[0] = a0; cnts[1] = a1;
    }
    __syncthreads();
    int run0 = w0[w] + (s0 - c0);
    int run1 = w1[w] + (s1 - c1);
#pragma unroll
    for (int j = 0; j < 4; ++j) {
        const int r = t * 4 + j;
        if (f0[j]) in0[run0++] = r; else z0[r - run0] = r;
        if (f1[j]) in1[run1++] = r; else z1[r - run1] = r;
    }
}

// ===========================================================================
// L1: fused casts (5 segments, f32 -> bf16, zero row padding). (R7 verbatim)
// ===========================================================================
struct CastSeg {
    const float* srcA;
    const float* srcB;
    unsigned short* dst;
    long rowsA, rowsB, total8;
    int lk, pad;
};
struct CastArgs {
    CastSeg s[5];
    long grand8;
};

__global__ __launch_bounds__(256)
void cast_kernel(CastArgs a) {
    long i = blockIdx.x * 256L + threadIdx.x;
    const long stride = (long)gridDim.x * 256L;
    for (; i < a.grand8; i += stride) {
        long off = i;
        int s = 0;
        while (s < 4 && off >= a.s[s].total8) { off -= a.s[s].total8; s++; }
        const CastSeg& sg = a.s[s];
        const long e   = off << 3;
        const long row = e >> sg.lk;
        ushort8 o;
        const float* src = nullptr;
        long r2 = row;
        if (row < sg.rowsA)      src = sg.srcA;
        else if (row < sg.rowsB) { src = sg.srcB; r2 = row - sg.rowsA; }
        if (src) {
            const long col = e & ((1L << sg.lk) - 1);
            const float* p = src + (r2 << sg.lk) + col;
            const float4 v0 = *(const float4*)(p);
            const float4 v1 = *(const float4*)(p + 4);
            o[0] = f2bf(v0.x); o[1] = f2bf(v0.y); o[2] = f2bf(v0.z); o[3] = f2bf(v0.w);
            o[4] = f2bf(v1.x); o[5] = f2bf(v1.y); o[6] = f2bf(v1.z); o[7] = f2bf(v1.w);
        } else {
            o = (ushort8)0;
        }
        *(ushort8*)(sg.dst + e) = o;
    }
}

// ===========================================================================
// L2: 8-phase 256x256 BK=64 GEMM, dual-config (head f32-out | h01 bf16-out).
// R7 verbatim (best-measured head path).
// ===========================================================================
#define STAGE2(MATP, LDM, RB, KCOL, LOFF)                                          \
    do {                                                                           \
        const unsigned short* _s0 = (MATP) + ((long)((RB) + (tid >> 3))) * (LDM) + (KCOL); \
        gload16(_s0, smem + (LOFF) + wave * 1024);                                 \
        const unsigned short* _s1 = (MATP) + ((long)((RB) + 64 + (tid >> 3))) * (LDM) + (KCOL); \
        gload16(_s1, smem + (LOFF) + 8192 + wave * 1024);                          \
    } while (0)

__global__ __launch_bounds__(512, 2)
void gemm8_dual_kernel(const unsigned short* __restrict__ A0,
                       const unsigned short* __restrict__ B0,
                       float* __restrict__ C0,
                       int nkt0, int lda0, int ldb0, int width0, int NB0, int nblk0,
                       const unsigned short* __restrict__ A1,
                       const unsigned short* __restrict__ B1,
                       unsigned short* __restrict__ C1,
                       int nkt1, int lda1, int ldb1, long ldc1, int width1, int NB1) {
    __shared__ char smem[131072];

    const int tid  = threadIdx.x;
    const int lane = tid & 63;
    const int wave = tid >> 6;
    const int wr   = wave >> 2;
    const int wc   = wave & 3;

    const bool isHead = (int)blockIdx.x < nblk0;
    const unsigned short* A = isHead ? A0 : A1;
    const unsigned short* B = isHead ? B0 : B1;
    const int nkt   = isHead ? nkt0 : nkt1;
    const int lda   = isHead ? lda0 : lda1;
    const int ldb   = isHead ? ldb0 : ldb1;
    const int width = isHead ? width0 : width1;
    const int NB    = isHead ? NB0 : NB1;
    const int lbid  = isHead ? blockIdx.x : blockIdx.x - nblk0;
    const int nwg   = isHead ? nblk0 : (int)gridDim.x - nblk0;

    const int q = nwg >> 3, r = nwg & 7;
    const int xcd = lbid & 7, loc = lbid >> 3;
    const int L = (xcd < r ? xcd * (q + 1) : r * (q + 1) + (xcd - r) * q) + loc;
    const int g = L / (NB * 4);
    const int t = L - g * (NB * 4);
    const long bm = g * 4 + (t & 3);
    const long bn = t >> 2;

    const long bmRow = bm * 256;
    const long bnRow = bn * 256;

    const int scol = (((tid & 7) ^ ((tid >> 3) & 7)) << 3);

    const unsigned lane15 = lane & 15;
    const unsigned rsw   = (lane15 & 7) << 4;
    const unsigned kcol0 = (((lane >> 4) << 4)) ^ rsw;
    const unsigned kcol1 = (64u + ((lane >> 4) << 4)) ^ rsw;
    const unsigned smemBase =
        (unsigned)(size_t)(__attribute__((address_space(3))) char*)smem;
    const unsigned aB0 = smemBase + wr * 16384 + lane15 * 128;
    const unsigned bB0 = smemBase + 32768 + (wc >> 1) * 16384 +
                         ((wc & 1) * 64 + lane15) * 128;

    f32x4 acc[8][4];
#pragma unroll
    for (int m = 0; m < 8; m++)
#pragma unroll
        for (int n = 0; n < 4; n++) acc[m][n] = (f32x4){0.f, 0.f, 0.f, 0.f};

    STAGE2(A, lda, bmRow,       scol, 0);
    STAGE2(A, lda, bmRow + 128, scol, 16384);
    STAGE2(B, ldb, bnRow,       scol, 32768);
    STAGE2(B, ldb, bnRow + 128, scol, 49152);

    short8 afk0[4], afk1[4], bA0[2], bA1[2], bH0[2], bH1[2];

    for (int kt = 0; kt < nkt; ++kt) {
        const int c  = kt & 1;
        const bool pf = (kt + 1) < nkt;
        const int kc = (kt + 1) * 64 + scol;
        const unsigned aBase = aB0 + c * 65536;
        const unsigned bBase = bB0 + c * 65536;
        const unsigned lOff  = (c ^ 1) * 65536;

        // phase 0 : Q0
        if (pf) {
            STAGE2(A, lda, bmRow, kc, lOff);
            asm volatile("s_waitcnt vmcnt(2)" ::: "memory");
        } else {
            asm volatile("s_waitcnt vmcnt(0)" ::: "memory");
        }
        __builtin_amdgcn_s_barrier();
#pragma unroll
        for (int mf = 0; mf < 4; ++mf) {
            afk0[mf] = dsr128(aBase + mf * 2048 + kcol0);
            afk1[mf] = dsr128(aBase + mf * 2048 + kcol1);
        }
#pragma unroll
        for (int nf = 0; nf < 2; ++nf) {
            bA0[nf] = dsr128(bBase + nf * 2048 + kcol0);
            bA1[nf] = dsr128(bBase + nf * 2048 + kcol1);
        }
        asm volatile("s_waitcnt lgkmcnt(0)" ::: "memory");
        __builtin_amdgcn_sched_barrier(0);
        __builtin_amdgcn_s_setprio(1);
#pragma unroll
        for (int mf = 0; mf < 4; ++mf)
#pragma unroll
            for (int nf = 0; nf < 2; ++nf) {
                acc[mf][nf] = mfma16(bA0[nf], afk0[mf], acc[mf][nf]);
                acc[mf][nf] = mfma16(bA1[nf], afk1[mf], acc[mf][nf]);
            }
        __builtin_amdgcn_s_setprio(0);
        __builtin_amdgcn_s_barrier();

        // phase 1 : Q1
#pragma unroll
        for (int nf = 0; nf < 2; ++nf) {
            bH0[nf] = dsr128(bBase + (2 + nf) * 2048 + kcol0);
            bH1[nf] = dsr128(bBase + (2 + nf) * 2048 + kcol1);
        }
        if (pf) STAGE2(A, lda, bmRow + 128, kc, lOff + 16384);
        __builtin_amdgcn_s_barrier();
        asm volatile("s_waitcnt lgkmcnt(0)" ::: "memory");
        __builtin_amdgcn_sched_barrier(0);
        __builtin_amdgcn_s_setprio(1);
#pragma unroll
        for (int mf = 0; mf < 4; ++mf)
#pragma unroll
            for (int nf = 0; nf < 2; ++nf) {
                acc[mf][2 + nf] = mfma16(bH0[nf], afk0[mf], acc[mf][2 + nf]);
                acc[mf][2 + nf] = mfma16(bH1[nf], afk1[mf], acc[mf][2 + nf]);
            }
        __builtin_amdgcn_s_setprio(0);
        __builtin_amdgcn_s_barrier();

        // phase 2 : Q2
#pragma unroll
        for (int mf = 0; mf < 4; ++mf) {
            afk0[mf] = dsr128(aBase + (4 + mf) * 2048 + kcol0);
            afk1[mf] = dsr128(aBase + (4 + mf) * 2048 + kcol1);
        }
        if (pf) STAGE2(B, ldb, bnRow, kc, lOff + 32768);
        __builtin_amdgcn_s_barrier();
        asm volatile("s_waitcnt lgkmcnt(0)" ::: "memory");
        __builtin_amdgcn_sched_barrier(0);
        __builtin_amdgcn_s_setprio(1);
#pragma unroll
        for (int mf = 0; mf < 4; ++mf)
#pragma unroll
            for (int nf = 0; nf < 2; ++nf) {
                acc[4 + mf][2 + nf] = mfma16(bH0[nf], afk0[mf], acc[4 + mf][2 + nf]);
                acc[4 + mf][2 + nf] = mfma16(bH1[nf], afk1[mf], acc[4 + mf][2 + nf]);
            }
        __builtin_amdgcn_s_setprio(0);
        __builtin_amdgcn_s_barrier();

        // phase 3 : Q3
#pragma unroll
        for (int nf = 0; nf < 2; ++nf) {
            bA0[nf] = dsr128(bBase + nf * 2048 + kcol0);
            bA1[nf] = dsr128(bBase + nf * 2048 + kcol1);
        }
        if (pf) STAGE2(B, ldb, bnRow + 128, kc, lOff + 49152);
        __builtin_amdgcn_s_barrier();
        asm volatile("s_waitcnt lgkmcnt(0)" ::: "memory");
        __builtin_amdgcn_sched_barrier(0);
        __builtin_amdgcn_s_setprio(1);
#pragma unroll
        for (int mf = 0; mf < 4; ++mf)
#pragma unroll
            for (int nf = 0; nf < 2; ++nf) {
                acc[4 + mf][nf] = mfma16(bA0[nf], afk0[mf], acc[4 + mf][nf]);
                acc[4 + mf][nf] = mfma16(bA1[nf], afk1[mf], acc[4 + mf][nf]);
            }
        __builtin_amdgcn_s_setprio(0);
        __builtin_amdgcn_s_barrier();
    }

    const int cb4 = (lane >> 4) << 2;
    if (isHead) {
        // transposed coalesced epilogue: LDS [128][256] f32, 2 passes
        for (int h = 0; h < 2; ++h) {
            __syncthreads();
            if (wr == h) {
#pragma unroll
                for (int mf = 0; mf < 8; ++mf) {
                    const int rl = mf * 16 + (int)lane15;
#pragma unroll
                    for (int nf = 0; nf < 4; ++nf) {
                        const int slot = wc * 16 + nf * 4 + (lane >> 4);
                        const int sl = slot ^ (rl & 7);
                        *(f32x4*)(smem + rl * 1024 + sl * 16) = acc[mf][nf];
                    }
                }
            }
            __syncthreads();
            const int colBase = (int)bnRow + lane * 4;
#pragma unroll
            for (int it = 0; it < 16; ++it) {
                const int rl = wave * 16 + it;
                const int sl = lane ^ (rl & 7);
                const f32x4 v = *(const f32x4*)(smem + rl * 1024 + sl * 16);
                float* rp = C0 + (bmRow + h * 128 + rl) * LDC;
                if (colBase + 3 < width) {
                    __builtin_memcpy(rp + colBase, &v, 16);
                } else {
#pragma unroll
                    for (int j = 0; j < 4; ++j)
                        if (colBase + j < width) rp[colBase + j] = v[j];
                }
            }
        }
    } else {
#pragma unroll
        for (int mf = 0; mf < 8; ++mf) {
            const long grow = bmRow + wr * 128 + mf * 16 + lane15;
            unsigned short* rp = C1 + grow * ldc1;
#pragma unroll
            for (int nf = 0; nf < 4; ++nf) {
                const int gcb = (int)bnRow + wc * 64 + nf * 16 + cb4;
                const f32x4 v = acc[mf][nf];
                ushort4 o;
                o.x = f2bf(v[0]); o.y = f2bf(v[1]); o.z = f2bf(v[2]); o.w = f2bf(v[3]);
                if (gcb + 3 < width) {
                    *(ushort4*)(rp + gcb) = o;
                } else {
                    unsigned short tmp[4] = {o.x, o.y, o.z, o.w};
#pragma unroll
                    for (int j = 0; j < 4; ++j)
                        if (gcb + j < width) rp[gcb + j] = tmp[j];
                }
            }
        }
    }
}

// ===========================================================================
// L3: compacted tails, BK=64 (4 iters t0, 1 iter t1), rule-21 swizzled
// staging/reads, transposed coalesced epilogue with NT scalar stores.
// Idle/finished blocks zero-fill masked tail rows with NT stores.
// ===========================================================================
__global__ __launch_bounds__(256)
void gemm_tails_kernel(const unsigned short* __restrict__ A0,
                       const unsigned short* __restrict__ B0,
                       float* __restrict__ C0,
                       int K0, int lda0, int width0, int NB0, int nblk0,
                       const unsigned short* __restrict__ A1,
                       const unsigned short* __restrict__ B1,
                       float* __restrict__ C1,
                       int K1, int lda1, int width1, int NB1,
                       const int* __restrict__ in0,
                       const int* __restrict__ in1,
                       const int* __restrict__ z0,
                       const int* __restrict__ z1,
                       const int* __restrict__ cnts) {
    __shared__ char tsm[32768];

    const int tid  = threadIdx.x;
    const int lane = tid & 63;
    const int wave = tid >> 6;
    const int wr   = wave >> 1;
    const int wc   = wave & 1;

    const bool is0 = (int)blockIdx.x < nblk0;
    const unsigned short* A = is0 ? A0 : A1;
    const unsigned short* B = is0 ? B0 : B1;
    float* Cf               = is0 ? C0 : C1;
    const int* rowlist      = is0 ? in0 : in1;
    const int cnt           = cnts[is0 ? 0 : 1];
    const int K     = is0 ? K0 : K1;
    const int lda   = is0 ? lda0 : lda1;
    const int width = is0 ? width0 : width1;
    const int NB    = is0 ? NB0 : NB1;
    const int lbid  = is0 ? blockIdx.x : blockIdx.x - nblk0;
    const int nwg   = is0 ? nblk0 : (int)gridDim.x - nblk0;

    const int q = nwg >> 3, r = nwg & 7;
    const int xcd = lbid & 7, loc = lbid >> 3;
    const int L = (xcd < r ? xcd * (q + 1) : r * (q + 1) + (xcd - r) * q) + loc;
    const int g = L / (NB << 3);
    const int t = L - g * (NB << 3);
    const long bm = (g << 3) + (t & 7);
    const long bn = t >> 3;

    const bool active = (int)(bm * 128) < cnt;

    if (active) {
        const int cm1 = cnt - 1;
        // staging: thread covers row s_row (+32g), pre-swizzled col chunk
        const int s_row = tid >> 3;                       // 0..31
        const int sc    = (((tid & 7) ^ (s_row & 7)) << 3);  // elem col

        int ar[4];
#pragma unroll
        for (int gg = 0; gg < 4; ++gg) {
            const int gi = (int)(bm * 128) + s_row + 32 * gg;
            ar[gg] = rowlist[gi < cnt ? gi : cm1];
        }
        const unsigned short* pB0 = B + (bn * 128 + s_row) * (long)K + sc;

        f32x4 acc[4][4];
#pragma unroll
        for (int m = 0; m < 4; m++)
#pragma unroll
            for (int n = 0; n < 4; n++) acc[m][n] = (f32x4){0.f, 0.f, 0.f, 0.f};

        const int f_r = lane & 15;
        const int fkb = (lane >> 4) << 4;   // byte offset of k-chunk in half

        for (int k0 = 0; k0 < K; k0 += 64) {
            // stage A[128][64] at 0, B[128][64] at 16384 (8 gloads/thread)
#pragma unroll
            for (int gg = 0; gg < 4; ++gg) {
                gload16(A + (long)ar[gg] * lda + sc + k0,
                        tsm + gg * 4096 + wave * 1024);
                gload16(pB0 + (long)(32 * gg) * K + k0,
                        tsm + 16384 + gg * 4096 + wave * 1024);
            }
            __syncthreads();

#pragma unroll
            for (int h = 0; h < 2; ++h) {
                short8 af[4], bfr[4];
#pragma unroll
                for (int m = 0; m < 4; m++) {
                    const int row = wr * 64 + m * 16 + f_r;
                    const int cb = (h * 64 + fkb) ^ ((row & 7) << 4);
                    af[m] = *(const short8*)(tsm + row * 128 + cb);
                }
#pragma unroll
                for (int n = 0; n < 4; n++) {
                    const int row = wc * 64 + n * 16 + f_r;
                    const int cb = (h * 64 + fkb) ^ ((row & 7) << 4);
                    bfr[n] = *(const short8*)(tsm + 16384 + row * 128 + cb);
                }
#pragma unroll
                for (int m = 0; m < 4; m++)
#pragma unroll
                    for (int n = 0; n < 4; n++)
                        acc[m][n] = mfma16(bfr[n], af[m], acc[m][n]);
            }
            __syncthreads();
        }

        // ---- transposed coalesced epilogue: LDS [64][128] f32, 2 passes ----
        const int c_a  = lane & 15;
        const int colL = (lane & 31) * 4;
        for (int h = 0; h < 2; ++h) {
            __syncthreads();
            if (wr == h) {
#pragma unroll
                for (int m = 0; m < 4; ++m) {
                    const int rl = m * 16 + c_a;
#pragma unroll
                    for (int n = 0; n < 4; ++n) {
                        const int slot = wc * 16 + n * 4 + (lane >> 4);
                        const int sl = slot ^ (rl & 7);
                        *(f32x4*)(tsm + rl * 512 + sl * 16) = acc[m][n];
                    }
                }
            }
            __syncthreads();
#pragma unroll
            for (int it = 0; it < 8; ++it) {
                const int rl = wave * 16 + it * 2 + (lane >> 5);
                const int gri = (int)(bm * 128) + h * 64 + rl;
                if (gri < cnt) {
                    const int sl = (lane & 31) ^ (rl & 7);
                    const f32x4 v = *(const f32x4*)(tsm + rl * 512 + sl * 16);
                    const long orow = rowlist[gri];
                    float* rp = Cf + orow * LDC;
                    const int col = (int)(bn * 128) + colL;
                    if (col + 3 < width) {
                        nt4(rp + col, v);
                    } else {
#pragma unroll
                        for (int j = 0; j < 4; ++j)
                            if (col + j < width)
                                __builtin_nontemporal_store(v[j], rp + col + j);
                    }
                }
            }
        }
    }

    // ---- zero-fill of masked tail rows (idle blocks start immediately) ----
    {
        const f32x4 zv = {0.f, 0.f, 0.f, 0.f};
        const int zc = 4096 - cnt;
        const int* zl = is0 ? z0 : z1;
        for (int s = lbid; s < zc; s += nwg) {
            const int rr = zl[s];
            float* base = Cf + (long)rr * LDC;
            for (int j = tid * 4; j + 3 < width; j += 1024)
                nt4(base + j, zv);
            for (int j = (width & ~3) + tid; j < width; j += 256)
                __builtin_nontemporal_store(0.f, base + j);
        }
    }
}

extern "C" void kernel_launch(void* const* d_in, const int* in_sizes, int n_in,
                              void* d_out, int out_size, void* d_ws, size_t ws_size,
                              hipStream_t stream) {
    const float* x      = (const float*)d_in[0];   // [4096,1024]
    const int*   target = (const int*)  d_in[1];   // [4096]
    const float* head_w = (const float*)d_in[2];   // [10002,1024]
    const float* t0_w1  = (const float*)d_in[3];   // [256,1024]
    const float* t0_w2  = (const float*)d_in[4];   // [30000,256]
    const float* t1_w1  = (const float*)d_in[5];   // [64,1024]
    const float* t1_w2  = (const float*)d_in[6];   // [10257,64]
    float* out = (float*)d_out;

    // ---- ws layout (bytes) ----
    char* ws = (char*)d_ws;
    unsigned short* xb    = (unsigned short*)(ws + 0);          // 4096x1024
    unsigned short* hwb   = (unsigned short*)(ws + 8388608);    // 10240x1024
    unsigned short* w01b  = (unsigned short*)(ws + 29360128);   // 512x1024 (t0w1|t1w1|0)
    unsigned short* t0w2b = (unsigned short*)(ws + 30408704);   // 30208x256
    unsigned short* t1w2b = (unsigned short*)(ws + 45875200);   // 10496x64
    unsigned short* h01   = (unsigned short*)(ws + 47218688);   // 4096x384 bf16
    int*            in0   = (int*)(ws + 50364416);              // 4096
    int*            z0l   = (int*)(ws + 50380800);              // 4096
    int*            in1   = (int*)(ws + 50397184);              // 4096
    int*            z1l   = (int*)(ws + 50413568);              // 4096
    int*            cnts  = (int*)(ws + 50429952);              // 2

    // ---- L0: scan (target remap + compaction lists) ----
    scan_kernel<<<1, 1024, 0, stream>>>(target, out + 4096L * LDC,
                                        in0, z0l, in1, z1l, cnts);

    // ---- L1: casts ----
    CastArgs ca;
    ca.s[0] = {x,      nullptr, xb,    4096,  4096,  524288,  10, 0};
    ca.s[1] = {head_w, nullptr, hwb,   10002, 10002, 1310720, 10, 0};
    ca.s[2] = {t0_w1,  t1_w1,   w01b,  256,   320,   65536,   10, 0};
    ca.s[3] = {t0_w2,  nullptr, t0w2b, 30000, 30000, 966656,  8,  0};
    ca.s[4] = {t1_w2,  nullptr, t1w2b, 10257, 10257, 83968,   6,  0};
    ca.grand8 = 524288 + 1310720 + 65536 + 966656 + 83968;  // 2951168
    cast_kernel<<<2048, 256, 0, stream>>>(ca);

    // ---- L2: head (640 blocks, 8-phase) + h01 (32 blocks) ----
    gemm8_dual_kernel<<<dim3(672), 512, 0, stream>>>(
        xb, hwb, out, 16, 1024, 1024, 10002, 40, 640,
        xb, w01b, h01, 16, 1024, 1024, 384L, 384, 2);

    // ---- L3: compacted tails (BK=64) + zero-fills (early-exit blocks) ----
    gemm_tails_kernel<<<dim3(10112), 256, 0, stream>>>(
        h01,       t0w2b, out + 10002, 256, 384, 30000, 235, 7520,
        h01 + 256, t1w2b, out + 40002, 64,  384, 10257, 81,
        in0, in1, z0l, z1l, cnts);
}

// Round 11
// 341.799 us; speedup vs baseline: 1.3192x; 1.0694x over previous
//
#include <hip/hip_runtime.h>
#include <hip/hip_bf16.h>
#include <stdint.h>

// ---------------------------------------------------------------------------
// FacebookAdaptiveSoftmax forward on MI355X (gfx950) — R11
//   out[4096, 50259] = concat(x@head_w^T, (x@t0w1^T)@t0w2^T * m0, (x@t1w1^T)@t1w2^T * m1)
//   new_head_target[4096] appended flat (as float)
// R11 = R10 with ONE change: zero-fills of masked tail rows move from L3 into
// the L2 launch as dedicated fill blocks (period-10 ID interleave with the
// 672 GEMM blocks). While ~2/3 of CUs run compute-bound head blocks (~2.5TB/s
// writes), fill blocks on the other CUs stream the 332MB of zeros with NT
// stores -> idle write BW soaked, head B-panels not evicted. L3 = pure tails.
// ---------------------------------------------------------------------------

typedef float  f32x4   __attribute__((ext_vector_type(4)));
typedef short  short8  __attribute__((ext_vector_type(8)));
typedef unsigned short ushort8 __attribute__((ext_vector_type(8)));

#define CUT0 10000
#define CUT1 40000
#define CUT2 50257
#define LDC   50259L

__device__ __forceinline__ void gload16(const void* g, void* l) {
    __builtin_amdgcn_global_load_lds(
        (__attribute__((address_space(1))) void*)(g),
        (__attribute__((address_space(3))) void*)(l), 16, 0, 0);
}

__device__ __forceinline__ unsigned short f2bf(float f) {
    unsigned int u = __float_as_uint(f);
    u += 0x7fffu + ((u >> 16) & 1u);   // round-to-nearest-even
    return (unsigned short)(u >> 16);
}

__device__ __forceinline__ short8 dsr128(unsigned addr) {
    f32x4 r;
    asm volatile("ds_read_b128 %0, %1" : "=v"(r) : "v"(addr));
    return __builtin_bit_cast(short8, r);
}

__device__ __forceinline__ f32x4 mfma16(short8 a, short8 b, f32x4 c) {
    return __builtin_amdgcn_mfma_f32_16x16x32_bf16(a, b, c, 0, 0, 0);
}

__device__ __forceinline__ void nt4(float* p, f32x4 v) {
    __builtin_nontemporal_store(v[0], p);
    __builtin_nontemporal_store(v[1], p + 1);
    __builtin_nontemporal_store(v[2], p + 2);
    __builtin_nontemporal_store(v[3], p + 3);
}

// ===========================================================================
// L0: target remap + order-preserving compaction scan (1 block, 1024 thr).
// ===========================================================================
__global__ __launch_bounds__(1024)
void scan_kernel(const int* __restrict__ tgt, float* __restrict__ outT,
                 int* __restrict__ in0, int* __restrict__ z0,
                 int* __restrict__ in1, int* __restrict__ z1,
                 int* __restrict__ cnts) {
    __shared__ int w0[16], w1[16];
    const int t = threadIdx.x;
    int f0[4], f1[4];
    int c0 = 0, c1 = 0;
#pragma unroll
    for (int j = 0; j < 4; ++j) {
        const int r = t * 4 + j;
        const int v = tgt[r];
        const int b0 = (v >= CUT0) && (v < CUT1);
        const int b1 = (v >= CUT1) && (v < CUT2);
        f0[j] = b0; f1[j] = b1;
        c0 += b0; c1 += b1;
        outT[r] = (float)(b0 ? CUT0 : (b1 ? CUT0 + 1 : v));
    }
    const int lane = t & 63, w = t >> 6;
    int s0 = c0, s1 = c1;
    for (int d = 1; d < 64; d <<= 1) {
        const int u0 = __shfl_up(s0, d, 64);
        const int u1 = __shfl_up(s1, d, 64);
        if (lane >= d) { s0 += u0; s1 += u1; }
    }
    if (lane == 63) { w0[w] = s0; w1[w] = s1; }
    __syncthreads();
    if (t == 0) {
        int a0 = 0, a1 = 0;
        for (int i = 0; i < 16; ++i) {
            const int x0 = w0[i]; w0[i] = a0; a0 += x0;
            const int x1 = w1[i]; w1[i] = a1; a1 += x1;
        }
        cnts[0] = a0; cnts[1] = a1;
    }
    __syncthreads();
    int run0 = w0[w] + (s0 - c0);
    int run1 = w1[w] + (s1 - c1);
#pragma unroll
    for (int j = 0; j < 4; ++j) {
        const int r = t * 4 + j;
        if (f0[j]) in0[run0++] = r; else z0[r - run0] = r;
        if (f1[j]) in1[run1++] = r; else z1[r - run1] = r;
    }
}

// ===========================================================================
// L1: fused casts (5 segments, f32 -> bf16, zero row padding). (R10 verbatim)
// ===========================================================================
struct CastSeg {
    const float* srcA;
    const float* srcB;
    unsigned short* dst;
    long rowsA, rowsB, total8;
    int lk, pad;
};
struct CastArgs {
    CastSeg s[5];
    long grand8;
};

__global__ __launch_bounds__(256)
void cast_kernel(CastArgs a) {
    long i = blockIdx.x * 256L + threadIdx.x;
    const long stride = (long)gridDim.x * 256L;
    for (; i < a.grand8; i += stride) {
        long off = i;
        int s = 0;
        while (s < 4 && off >= a.s[s].total8) { off -= a.s[s].total8; s++; }
        const CastSeg& sg = a.s[s];
        const long e   = off << 3;
        const long row = e >> sg.lk;
        ushort8 o;
        const float* src = nullptr;
        long r2 = row;
        if (row < sg.rowsA)      src = sg.srcA;
        else if (row < sg.rowsB) { src = sg.srcB; r2 = row - sg.rowsA; }
        if (src) {
            const long col = e & ((1L << sg.lk) - 1);
            const float* p = src + (r2 << sg.lk) + col;
            const float4 v0 = *(const float4*)(p);
            const float4 v1 = *(const float4*)(p + 4);
            o[0] = f2bf(v0.x); o[1] = f2bf(v0.y); o[2] = f2bf(v0.z); o[3] = f2bf(v0.w);
            o[4] = f2bf(v1.x); o[5] = f2bf(v1.y); o[6] = f2bf(v1.z); o[7] = f2bf(v1.w);
        } else {
            o = (ushort8)0;
        }
        *(ushort8*)(sg.dst + e) = o;
    }
}

// ===========================================================================
// L2: 8-phase 256x256 BK=64 GEMM (head f32-out | h01 bf16-out) + interleaved
// dedicated FILL blocks (zero masked tail rows, NT stores).
// Grid 2240 = 224 periods x 10 ids: pos {0,3,6} = GEMM (672), others = fill
// (1568: fidx<768 -> tail0 rows strided 768; else tail1 rows strided 800).
// ===========================================================================
#define STAGE2(MATP, LDM, RB, KCOL, LOFF)                                          \
    do {                                                                           \
        const unsigned short* _s0 = (MATP) + ((long)((RB) + (tid >> 3))) * (LDM) + (KCOL); \
        gload16(_s0, smem + (LOFF) + wave * 1024);                                 \
        const unsigned short* _s1 = (MATP) + ((long)((RB) + 64 + (tid >> 3))) * (LDM) + (KCOL); \
        gload16(_s1, smem + (LOFF) + 8192 + wave * 1024);                          \
    } while (0)

__global__ __launch_bounds__(512, 2)
void gemm8_dual_kernel(const unsigned short* __restrict__ A0,
                       const unsigned short* __restrict__ B0,
                       float* __restrict__ C0,
                       int nkt0, int lda0, int ldb0, int width0, int NB0, int nblk0,
                       const unsigned short* __restrict__ A1,
                       const unsigned short* __restrict__ B1,
                       unsigned short* __restrict__ C1,
                       int nkt1, int lda1, int ldb1, long ldc1, int width1, int NB1,
                       const int* __restrict__ z0, const int* __restrict__ z1,
                       const int* __restrict__ cnts, float* __restrict__ outFull) {
    __shared__ char smem[131072];

    const int tid  = threadIdx.x;
    const int lane = tid & 63;
    const int wave = tid >> 6;
    const int wr   = wave >> 2;
    const int wc   = wave & 3;

    // ---- id -> {GEMM gid | fill fidx} (period-10 interleave) ----
    const int pid = blockIdx.x / 10;
    const int pos = blockIdx.x - 10 * pid;
    const bool isGemm = (pos == 0) || (pos == 3) || (pos == 6);

    if (!isGemm) {
        // fill-block: fmap 1,2,4,5,7,8,9 -> 0..6
        const int fmap = (pos < 3) ? (pos - 1) : (pos < 6 ? pos - 2 : pos - 3);
        const int fidx = pid * 7 + fmap;
        const bool isT0 = fidx < 768;
        const int zc = 4096 - cnts[isT0 ? 0 : 1];
        const int* zl = isT0 ? z0 : z1;
        float* base0 = outFull + (isT0 ? 10002 : 40002);
        const int width = isT0 ? 30000 : 10257;
        const int fstride = isT0 ? 768 : 800;
        const f32x4 zv = {0.f, 0.f, 0.f, 0.f};
        for (int s = isT0 ? fidx : fidx - 768; s < zc; s += fstride) {
            float* base = base0 + (long)zl[s] * LDC;
            for (int j = tid * 4; j + 3 < width; j += 2048)
                nt4(base + j, zv);
            for (int j = (width & ~3) + tid; j < width; j += 512)
                __builtin_nontemporal_store(0.f, base + j);
        }
        return;
    }

    const int gid = pid * 3 + (pos == 0 ? 0 : (pos == 3 ? 1 : 2));
    const bool isHead = gid < nblk0;
    const unsigned short* A = isHead ? A0 : A1;
    const unsigned short* B = isHead ? B0 : B1;
    const int nkt   = isHead ? nkt0 : nkt1;
    const int lda   = isHead ? lda0 : lda1;
    const int ldb   = isHead ? ldb0 : ldb1;
    const int width = isHead ? width0 : width1;
    const int NB    = isHead ? NB0 : NB1;
    const int lbid  = isHead ? gid : gid - nblk0;
    const int nwg   = isHead ? nblk0 : 672 - nblk0;

    const int q = nwg >> 3, r = nwg & 7;
    const int xcd = lbid & 7, loc = lbid >> 3;
    const int L = (xcd < r ? xcd * (q + 1) : r * (q + 1) + (xcd - r) * q) + loc;
    const int g = L / (NB * 4);
    const int t = L - g * (NB * 4);
    const long bm = g * 4 + (t & 3);
    const long bn = t >> 2;

    const long bmRow = bm * 256;
    const long bnRow = bn * 256;

    const int scol = (((tid & 7) ^ ((tid >> 3) & 7)) << 3);

    const unsigned lane15 = lane & 15;
    const unsigned rsw   = (lane15 & 7) << 4;
    const unsigned kcol0 = (((lane >> 4) << 4)) ^ rsw;
    const unsigned kcol1 = (64u + ((lane >> 4) << 4)) ^ rsw;
    const unsigned smemBase =
        (unsigned)(size_t)(__attribute__((address_space(3))) char*)smem;
    const unsigned aB0 = smemBase + wr * 16384 + lane15 * 128;
    const unsigned bB0 = smemBase + 32768 + (wc >> 1) * 16384 +
                         ((wc & 1) * 64 + lane15) * 128;

    f32x4 acc[8][4];
#pragma unroll
    for (int m = 0; m < 8; m++)
#pragma unroll
        for (int n = 0; n < 4; n++) acc[m][n] = (f32x4){0.f, 0.f, 0.f, 0.f};

    STAGE2(A, lda, bmRow,       scol, 0);
    STAGE2(A, lda, bmRow + 128, scol, 16384);
    STAGE2(B, ldb, bnRow,       scol, 32768);
    STAGE2(B, ldb, bnRow + 128, scol, 49152);

    short8 afk0[4], afk1[4], bA0[2], bA1[2], bH0[2], bH1[2];

    for (int kt = 0; kt < nkt; ++kt) {
        const int c  = kt & 1;
        const bool pf = (kt + 1) < nkt;
        const int kc = (kt + 1) * 64 + scol;
        const unsigned aBase = aB0 + c * 65536;
        const unsigned bBase = bB0 + c * 65536;
        const unsigned lOff  = (c ^ 1) * 65536;

        // phase 0 : Q0
        if (pf) {
            STAGE2(A, lda, bmRow, kc, lOff);
            asm volatile("s_waitcnt vmcnt(2)" ::: "memory");
        } else {
            asm volatile("s_waitcnt vmcnt(0)" ::: "memory");
        }
        __builtin_amdgcn_s_barrier();
#pragma unroll
        for (int mf = 0; mf < 4; ++mf) {
            afk0[mf] = dsr128(aBase + mf * 2048 + kcol0);
            afk1[mf] = dsr128(aBase + mf * 2048 + kcol1);
        }
#pragma unroll
        for (int nf = 0; nf < 2; ++nf) {
            bA0[nf] = dsr128(bBase + nf * 2048 + kcol0);
            bA1[nf] = dsr128(bBase + nf * 2048 + kcol1);
        }
        asm volatile("s_waitcnt lgkmcnt(0)" ::: "memory");
        __builtin_amdgcn_sched_barrier(0);
        __builtin_amdgcn_s_setprio(1);
#pragma unroll
        for (int mf = 0; mf < 4; ++mf)
#pragma unroll
            for (int nf = 0; nf < 2; ++nf) {
                acc[mf][nf] = mfma16(bA0[nf], afk0[mf], acc[mf][nf]);
                acc[mf][nf] = mfma16(bA1[nf], afk1[mf], acc[mf][nf]);
            }
        __builtin_amdgcn_s_setprio(0);
        __builtin_amdgcn_s_barrier();

        // phase 1 : Q1
#pragma unroll
        for (int nf = 0; nf < 2; ++nf) {
            bH0[nf] = dsr128(bBase + (2 + nf) * 2048 + kcol0);
            bH1[nf] = dsr128(bBase + (2 + nf) * 2048 + kcol1);
        }
        if (pf) STAGE2(A, lda, bmRow + 128, kc, lOff + 16384);
        __builtin_amdgcn_s_barrier();
        asm volatile("s_waitcnt lgkmcnt(0)" ::: "memory");
        __builtin_amdgcn_sched_barrier(0);
        __builtin_amdgcn_s_setprio(1);
#pragma unroll
        for (int mf = 0; mf < 4; ++mf)
#pragma unroll
            for (int nf = 0; nf < 2; ++nf) {
                acc[mf][2 + nf] = mfma16(bH0[nf], afk0[mf], acc[mf][2 + nf]);
                acc[mf][2 + nf] = mfma16(bH1[nf], afk1[mf], acc[mf][2 + nf]);
            }
        __builtin_amdgcn_s_setprio(0);
        __builtin_amdgcn_s_barrier();

        // phase 2 : Q2
#pragma unroll
        for (int mf = 0; mf < 4; ++mf) {
            afk0[mf] = dsr128(aBase + (4 + mf) * 2048 + kcol0);
            afk1[mf] = dsr128(aBase + (4 + mf) * 2048 + kcol1);
        }
        if (pf) STAGE2(B, ldb, bnRow, kc, lOff + 32768);
        __builtin_amdgcn_s_barrier();
        asm volatile("s_waitcnt lgkmcnt(0)" ::: "memory");
        __builtin_amdgcn_sched_barrier(0);
        __builtin_amdgcn_s_setprio(1);
#pragma unroll
        for (int mf = 0; mf < 4; ++mf)
#pragma unroll
            for (int nf = 0; nf < 2; ++nf) {
                acc[4 + mf][2 + nf] = mfma16(bH0[nf], afk0[mf], acc[4 + mf][2 + nf]);
                acc[4 + mf][2 + nf] = mfma16(bH1[nf], afk1[mf], acc[4 + mf][2 + nf]);
            }
        __builtin_amdgcn_s_setprio(0);
        __builtin_amdgcn_s_barrier();

        // phase 3 : Q3
#pragma unroll
        for (int nf = 0; nf < 2; ++nf) {
            bA0[nf] = dsr128(bBase + nf * 2048 + kcol0);
            bA1[nf] = dsr128(bBase + nf * 2048 + kcol1);
        }
        if (pf) STAGE2(B, ldb, bnRow + 128, kc, lOff + 49152);
        __builtin_amdgcn_s_barrier();
        asm volatile("s_waitcnt lgkmcnt(0)" ::: "memory");
        __builtin_amdgcn_sched_barrier(0);
        __builtin_amdgcn_s_setprio(1);
#pragma unroll
        for (int mf = 0; mf < 4; ++mf)
#pragma unroll
            for (int nf = 0; nf < 2; ++nf) {
                acc[4 + mf][nf] = mfma16(bA0[nf], afk0[mf], acc[4 + mf][nf]);
                acc[4 + mf][nf] = mfma16(bA1[nf], afk1[mf], acc[4 + mf][nf]);
            }
        __builtin_amdgcn_s_setprio(0);
        __builtin_amdgcn_s_barrier();
    }

    const int cb4 = (lane >> 4) << 2;
    if (isHead) {
        // transposed coalesced epilogue: LDS [128][256] f32, 2 passes
        for (int h = 0; h < 2; ++h) {
            __syncthreads();
            if (wr == h) {
#pragma unroll
                for (int mf = 0; mf < 8; ++mf) {
                    const int rl = mf * 16 + (int)lane15;
#pragma unroll
                    for (int nf = 0; nf < 4; ++nf) {
                        const int slot = wc * 16 + nf * 4 + (lane >> 4);
                        const int sl = slot ^ (rl & 7);
                        *(f32x4*)(smem + rl * 1024 + sl * 16) = acc[mf][nf];
                    }
                }
            }
            __syncthreads();
            const int colBase = (int)bnRow + lane * 4;
#pragma unroll
            for (int it = 0; it < 16; ++it) {
                const int rl = wave * 16 + it;
                const int sl = lane ^ (rl & 7);
                const f32x4 v = *(const f32x4*)(smem + rl * 1024 + sl * 16);
                float* rp = C0 + (bmRow + h * 128 + rl) * LDC;
                if (colBase + 3 < width) {
                    __builtin_memcpy(rp + colBase, &v, 16);
                } else {
#pragma unroll
                    for (int j = 0; j < 4; ++j)
                        if (colBase + j < width) rp[colBase + j] = v[j];
                }
            }
        }
    } else {
#pragma unroll
        for (int mf = 0; mf < 8; ++mf) {
            const long grow = bmRow + wr * 128 + mf * 16 + lane15;
            unsigned short* rp = C1 + grow * ldc1;
#pragma unroll
            for (int nf = 0; nf < 4; ++nf) {
                const int gcb = (int)bnRow + wc * 64 + nf * 16 + cb4;
                const f32x4 v = acc[mf][nf];
                ushort4 o;
                o.x = f2bf(v[0]); o.y = f2bf(v[1]); o.z = f2bf(v[2]); o.w = f2bf(v[3]);
                if (gcb + 3 < width) {
                    *(ushort4*)(rp + gcb) = o;
                } else {
                    unsigned short tmp[4] = {o.x, o.y, o.z, o.w};
#pragma unroll
                    for (int j = 0; j < 4; ++j)
                        if (gcb + j < width) rp[gcb + j] = tmp[j];
                }
            }
        }
    }
}

// ===========================================================================
// L3: compacted tails, BK=64, rule-21 swizzled staging/reads, transposed
// coalesced epilogue with NT scalar stores. (R10 minus the fill loop.)
// ===========================================================================
__global__ __launch_bounds__(256)
void gemm_tails_kernel(const unsigned short* __restrict__ A0,
                       const unsigned short* __restrict__ B0,
                       float* __restrict__ C0,
                       int K0, int lda0, int width0, int NB0, int nblk0,
                       const unsigned short* __restrict__ A1,
                       const unsigned short* __restrict__ B1,
                       float* __restrict__ C1,
                       int K1, int lda1, int width1, int NB1,
                       const int* __restrict__ in0,
                       const int* __restrict__ in1,
                       const int* __restrict__ cnts) {
    __shared__ char tsm[32768];

    const int tid  = threadIdx.x;
    const int lane = tid & 63;
    const int wave = tid >> 6;
    const int wr   = wave >> 1;
    const int wc   = wave & 1;

    const bool is0 = (int)blockIdx.x < nblk0;
    const unsigned short* A = is0 ? A0 : A1;
    const unsigned short* B = is0 ? B0 : B1;
    float* Cf               = is0 ? C0 : C1;
    const int* rowlist      = is0 ? in0 : in1;
    const int cnt           = cnts[is0 ? 0 : 1];
    const int K     = is0 ? K0 : K1;
    const int lda   = is0 ? lda0 : lda1;
    const int width = is0 ? width0 : width1;
    const int NB    = is0 ? NB0 : NB1;
    const int lbid  = is0 ? blockIdx.x : blockIdx.x - nblk0;
    const int nwg   = is0 ? nblk0 : (int)gridDim.x - nblk0;

    const int q = nwg >> 3, r = nwg & 7;
    const int xcd = lbid & 7, loc = lbid >> 3;
    const int L = (xcd < r ? xcd * (q + 1) : r * (q + 1) + (xcd - r) * q) + loc;
    const int g = L / (NB << 3);
    const int t = L - g * (NB << 3);
    const long bm = (g << 3) + (t & 7);
    const long bn = t >> 3;

    if ((int)(bm * 128) >= cnt) return;

    const int cm1 = cnt - 1;
    const int s_row = tid >> 3;                          // 0..31
    const int sc    = (((tid & 7) ^ (s_row & 7)) << 3);  // elem col

    int ar[4];
#pragma unroll
    for (int gg = 0; gg < 4; ++gg) {
        const int gi = (int)(bm * 128) + s_row + 32 * gg;
        ar[gg] = rowlist[gi < cnt ? gi : cm1];
    }
    const unsigned short* pB0 = B + (bn * 128 + s_row) * (long)K + sc;

    f32x4 acc[4][4];
#pragma unroll
    for (int m = 0; m < 4; m++)
#pragma unroll
        for (int n = 0; n < 4; n++) acc[m][n] = (f32x4){0.f, 0.f, 0.f, 0.f};

    const int f_r = lane & 15;
    const int fkb = (lane >> 4) << 4;   // byte offset of k-chunk in half

    for (int k0 = 0; k0 < K; k0 += 64) {
#pragma unroll
        for (int gg = 0; gg < 4; ++gg) {
            gload16(A + (long)ar[gg] * lda + sc + k0,
                    tsm + gg * 4096 + wave * 1024);
            gload16(pB0 + (long)(32 * gg) * K + k0,
                    tsm + 16384 + gg * 4096 + wave * 1024);
        }
        __syncthreads();

#pragma unroll
        for (int h = 0; h < 2; ++h) {
            short8 af[4], bfr[4];
#pragma unroll
            for (int m = 0; m < 4; m++) {
                const int row = wr * 64 + m * 16 + f_r;
                const int cb = (h * 64 + fkb) ^ ((row & 7) << 4);
                af[m] = *(const short8*)(tsm + row * 128 + cb);
            }
#pragma unroll
            for (int n = 0; n < 4; n++) {
                const int row = wc * 64 + n * 16 + f_r;
                const int cb = (h * 64 + fkb) ^ ((row & 7) << 4);
                bfr[n] = *(const short8*)(tsm + 16384 + row * 128 + cb);
            }
#pragma unroll
            for (int m = 0; m < 4; m++)
#pragma unroll
                for (int n = 0; n < 4; n++)
                    acc[m][n] = mfma16(bfr[n], af[m], acc[m][n]);
        }
        __syncthreads();
    }

    // ---- transposed coalesced epilogue: LDS [64][128] f32, 2 passes ----
    const int c_a  = lane & 15;
    const int colL = (lane & 31) * 4;
    for (int h = 0; h < 2; ++h) {
        __syncthreads();
        if (wr == h) {
#pragma unroll
            for (int m = 0; m < 4; ++m) {
                const int rl = m * 16 + c_a;
#pragma unroll
                for (int n = 0; n < 4; ++n) {
                    const int slot = wc * 16 + n * 4 + (lane >> 4);
                    const int sl = slot ^ (rl & 7);
                    *(f32x4*)(tsm + rl * 512 + sl * 16) = acc[m][n];
                }
            }
        }
        __syncthreads();
#pragma unroll
        for (int it = 0; it < 8; ++it) {
            const int rl = wave * 16 + it * 2 + (lane >> 5);
            const int gri = (int)(bm * 128) + h * 64 + rl;
            if (gri < cnt) {
                const int sl = (lane & 31) ^ (rl & 7);
                const f32x4 v = *(const f32x4*)(tsm + rl * 512 + sl * 16);
                const long orow = rowlist[gri];
                float* rp = Cf + orow * LDC;
                const int col = (int)(bn * 128) + colL;
                if (col + 3 < width) {
                    nt4(rp + col, v);
                } else {
#pragma unroll
                    for (int j = 0; j < 4; ++j)
                        if (col + j < width)
                            __builtin_nontemporal_store(v[j], rp + col + j);
                }
            }
        }
    }
}

extern "C" void kernel_launch(void* const* d_in, const int* in_sizes, int n_in,
                              void* d_out, int out_size, void* d_ws, size_t ws_size,
                              hipStream_t stream) {
    const float* x      = (const float*)d_in[0];   // [4096,1024]
    const int*   target = (const int*)  d_in[1];   // [4096]
    const float* head_w = (const float*)d_in[2];   // [10002,1024]
    const float* t0_w1  = (const float*)d_in[3];   // [256,1024]
    const float* t0_w2  = (const float*)d_in[4];   // [30000,256]
    const float* t1_w1  = (const float*)d_in[5];   // [64,1024]
    const float* t1_w2  = (const float*)d_in[6];   // [10257,64]
    float* out = (float*)d_out;

    // ---- ws layout (bytes) ----
    char* ws = (char*)d_ws;
    unsigned short* xb    = (unsigned short*)(ws + 0);          // 4096x1024
    unsigned short* hwb   = (unsigned short*)(ws + 8388608);    // 10240x1024
    unsigned short* w01b  = (unsigned short*)(ws + 29360128);   // 512x1024 (t0w1|t1w1|0)
    unsigned short* t0w2b = (unsigned short*)(ws + 30408704);   // 30208x256
    unsigned short* t1w2b = (unsigned short*)(ws + 45875200);   // 10496x64
    unsigned short* h01   = (unsigned short*)(ws + 47218688);   // 4096x384 bf16
    int*            in0   = (int*)(ws + 50364416);              // 4096
    int*            z0l   = (int*)(ws + 50380800);              // 4096
    int*            in1   = (int*)(ws + 50397184);              // 4096
    int*            z1l   = (int*)(ws + 50413568);              // 4096
    int*            cnts  = (int*)(ws + 50429952);              // 2

    // ---- L0: scan (target remap + compaction lists) ----
    scan_kernel<<<1, 1024, 0, stream>>>(target, out + 4096L * LDC,
                                        in0, z0l, in1, z1l, cnts);

    // ---- L1: casts ----
    CastArgs ca;
    ca.s[0] = {x,      nullptr, xb,    4096,  4096,  524288,  10, 0};
    ca.s[1] = {head_w, nullptr, hwb,   10002, 10002, 1310720, 10, 0};
    ca.s[2] = {t0_w1,  t1_w1,   w01b,  256,   320,   65536,   10, 0};
    ca.s[3] = {t0_w2,  nullptr, t0w2b, 30000, 30000, 966656,  8,  0};
    ca.s[4] = {t1_w2,  nullptr, t1w2b, 10257, 10257, 83968,   6,  0};
    ca.grand8 = 524288 + 1310720 + 65536 + 966656 + 83968;  // 2951168
    cast_kernel<<<2048, 256, 0, stream>>>(ca);

    // ---- L2: head (640) + h01 (32) GEMM blocks + 1568 fill blocks,
    //          period-10 interleave, grid 2240 ----
    gemm8_dual_kernel<<<dim3(2240), 512, 0, stream>>>(
        xb, hwb, out, 16, 1024, 1024, 10002, 40, 640,
        xb, w01b, h01, 16, 1024, 1024, 384L, 384, 2,
        z0l, z1l, cnts, out);

    // ---- L3: compacted tails only (BK=64) ----
    gemm_tails_kernel<<<dim3(10112), 256, 0, stream>>>(
        h01,       t0w2b, out + 10002, 256, 384, 30000, 235, 7520,
        h01 + 256, t1w2b, out + 40002, 64,  384, 10257, 81,
        in0, in1, cnts);
}